// Round 3
// baseline (158.416 us; speedup 1.0000x reference)
//
#include <hip/hip_runtime.h>

// Problem constants
constexpr int NB  = 1024;   // batch
constexpr int NIN = 512;    // input features
constexpr int NJ  = 64;     // J
constexpr int NK  = 8;      // K
constexpr int NC  = NJ * NK;          // 512 output cols of M
constexpr int OUTC = NIN + NJ;        // 576
constexpr float EXPN10 = 4.5399929762484854e-05f;  // exp(-10)
constexpr float FEAT_BASE = 1024.0f * EXPN10;      // all-clamped row sum

typedef __bf16 bf16x8 __attribute__((ext_vector_type(8)));
typedef float floatx16 __attribute__((ext_vector_type(16)));

__device__ __forceinline__ unsigned f2bf(float f) {  // RNE fp32->bf16 (no NaN here)
  unsigned u = __float_as_uint(f);
  u += 0x7FFFu + ((u >> 16) & 1u);
  return u >> 16;
}

// ---------------------------------------------------------------------------
// Kernel 1: Mp[j][b][k] += partial GEMM, split-K=4 via fp32 atomics.
// Grid (16 b-tiles, 8 c-tiles, 4 k-splits) = 512 blocks (2/CU).
// ---------------------------------------------------------------------------
__global__ __launch_bounds__(256) void gemm_kernel(const float* __restrict__ x,
                                                   const float* __restrict__ T,
                                                   float* __restrict__ Mp) {
  __shared__ __align__(16) float Xs[16][68];
  __shared__ __align__(16) float Ts[16][68];

  const int tid = threadIdx.x;
  const int b0 = blockIdx.x * 64;
  const int c0 = blockIdx.y * 64;
  const int kbeg = blockIdx.z * 128;
  const int tx = tid & 15;
  const int ty = tid >> 4;

  const int xr = tid >> 2;
  const int xi = (tid & 3) * 4;
  const int tr = tid >> 4;
  const int tc = (tid & 15) * 4;

  float acc[4][4] = {};

  for (int k0 = kbeg; k0 < kbeg + 128; k0 += 16) {
    float4 xv = *(const float4*)&x[(b0 + xr) * NIN + k0 + xi];
    Xs[xi + 0][xr] = xv.x;
    Xs[xi + 1][xr] = xv.y;
    Xs[xi + 2][xr] = xv.z;
    Xs[xi + 3][xr] = xv.w;
    float4 tv = *(const float4*)&T[(k0 + tr) * NC + c0 + tc];
    *(float4*)&Ts[tr][tc] = tv;
    __syncthreads();

#pragma unroll
    for (int kk = 0; kk < 16; ++kk) {
      float4 xa = *(const float4*)&Xs[kk][ty * 4];
      float4 tb = *(const float4*)&Ts[kk][tx * 4];
      const float xs[4] = {xa.x, xa.y, xa.z, xa.w};
      const float ts[4] = {tb.x, tb.y, tb.z, tb.w};
#pragma unroll
      for (int r = 0; r < 4; ++r)
#pragma unroll
        for (int c = 0; c < 4; ++c)
          acc[r][c] = fmaf(xs[r], ts[c], acc[r][c]);
    }
    __syncthreads();
  }

#pragma unroll
  for (int r = 0; r < 4; ++r) {
    const int b = b0 + ty * 4 + r;
#pragma unroll
    for (int c = 0; c < 4; ++c) {
      const int cc = c0 + tx * 4 + c;
      const int j = cc >> 3, k = cc & 7;
      atomicAdd(&Mp[(j * NB + b) * NK + k], acc[r][c]);
    }
  }
}

// ---------------------------------------------------------------------------
// Kernel 2: prep — Mb bf16 fragments (16B per (j,b)) + na = |M[j][b]|^2 fp32.
// ---------------------------------------------------------------------------
__global__ __launch_bounds__(256) void prep_kernel(const float* __restrict__ Mp,
                                                   uint4* __restrict__ Mb,
                                                   float* __restrict__ na) {
  const int idx = blockIdx.x * 256 + threadIdx.x;  // 0..65535 = j*1024+b
  const float4 m0 = ((const float4*)Mp)[idx * 2];
  const float4 m1 = ((const float4*)Mp)[idx * 2 + 1];
  float s = m0.x * m0.x;
  s = fmaf(m0.y, m0.y, s); s = fmaf(m0.z, m0.z, s); s = fmaf(m0.w, m0.w, s);
  s = fmaf(m1.x, m1.x, s); s = fmaf(m1.y, m1.y, s); s = fmaf(m1.z, m1.z, s);
  s = fmaf(m1.w, m1.w, s);
  na[idx] = s;
  uint4 p;
  p.x = f2bf(m0.x) | (f2bf(m0.y) << 16);
  p.y = f2bf(m0.z) | (f2bf(m0.w) << 16);
  p.z = f2bf(m1.x) | (f2bf(m1.y) << 16);
  p.w = f2bf(m1.z) | (f2bf(m1.w) << 16);
  Mb[idx] = p;
}

// ---------------------------------------------------------------------------
// Kernel 3: pairwise via MFMA. Grid (j=64, a-group=8, b-half=2) = 1024 blocks.
// Block: 4 waves; wave w owns a-tile of 32 rows (a0 = ag*128 + w*32),
// iterates 16 b-tiles of its 512-b half. K=8 zero-padded to 16:
// lanes<32 carry real k=0..7 data for BOTH operands; lanes>=32 carry zeros.
// Epilogue = detection only: feats base is the constant 1024*exp(-10), added
// in out_kernel; only rare near-pairs get exact fp32 corrections (atomicAdd).
// Conservative flag: sq_est < 300 + 0.01*(na+nb); bf16 error <= 0.004*(na+nb).
// ---------------------------------------------------------------------------
__global__ __launch_bounds__(256) void pairwise_kernel(const uint4* __restrict__ Mb,
                                                       const float* __restrict__ na,
                                                       const float* __restrict__ Mp,
                                                       float* __restrict__ feats) {
  const int j    = blockIdx.x;
  const int ag   = blockIdx.y;
  const int bh   = blockIdx.z;
  const int tid  = threadIdx.x;
  const int lane = tid & 63;
  const int w    = tid >> 6;
  const int col  = lane & 31;
  const int jb   = j * NB;

  __shared__ uint4 Mb_s[513];    // [512]=zeros for K-pad lanes
  __shared__ float nb_s[512];
  __shared__ float na_as[128];   // per-wave a-tile norms

  // stage the 512-b half: 8 KB fragments + 2 KB norms
  const int bbeg = bh * 512;
  Mb_s[tid]       = Mb[jb + bbeg + tid];
  Mb_s[tid + 256] = Mb[jb + bbeg + tid + 256];
  nb_s[tid]       = na[jb + bbeg + tid];
  nb_s[tid + 256] = na[jb + bbeg + tid + 256];
  if (tid == 0) Mb_s[512] = uint4{0u, 0u, 0u, 0u};

  // a-side: fragment + norms + wave-min of norms
  const int a0 = ag * 128 + w * 32;
  const float na_al = na[jb + a0 + col];
  if (lane < 32) na_as[w * 32 + lane] = na_al;
  float mn = na_al;
#pragma unroll
  for (int off = 1; off < 64; off <<= 1) mn = fminf(mn, __shfl_xor(mn, off));

  uint4 araw = uint4{0u, 0u, 0u, 0u};
  if (lane < 32) araw = Mb[jb + a0 + lane];
  const bf16x8 af = __builtin_bit_cast(bf16x8, araw);

  __syncthreads();

  const floatx16 zero = {};

#pragma unroll 4
  for (int bt = 0; bt < 16; ++bt) {
    const int bidx = bt * 32 + col;
    const uint4 braw = Mb_s[lane < 32 ? bidx : 512];
    const bf16x8 bf = __builtin_bit_cast(bf16x8, braw);
    const floatx16 P = __builtin_amdgcn_mfma_f32_32x32x16_bf16(af, bf, zero, 0, 0, 0);
    const float nb_l = nb_s[bidx];

    float pmax = P[0];
#pragma unroll
    for (int r = 1; r < 16; ++r) pmax = fmaxf(pmax, P[r]);
    // flag tile if any 2P > 0.99*(min_na+nb) - 300
    const float thr = 0.495f * (mn + nb_l) - 150.0f;

    if (__any(pmax > thr)) {   // rare: diagonal tiles + ~1e-5 of others
#pragma unroll
      for (int reg = 0; reg < 16; ++reg) {
        const int row = (reg & 3) + 8 * (reg >> 2) + 4 * (lane >> 5);
        const float na_r = na_as[w * 32 + row];
        const float S = na_r + nb_l;
        if (S - 2.0f * P[reg] < 300.0f + 0.01f * S) {
          const int a = a0 + row;
          const int b = bbeg + bt * 32 + col;
          float corr;
          if (a == b) {
            corr = 1.0f - EXPN10;           // exact diagonal
          } else {
            const float4 av0 = ((const float4*)Mp)[(jb + a) * 2];
            const float4 av1 = ((const float4*)Mp)[(jb + a) * 2 + 1];
            const float4 bv0 = ((const float4*)Mp)[(jb + b) * 2];
            const float4 bv1 = ((const float4*)Mp)[(jb + b) * 2 + 1];
            float d = av0.x - bv0.x; float sq = d * d;
            d = av0.y - bv0.y; sq = fmaf(d, d, sq);
            d = av0.z - bv0.z; sq = fmaf(d, d, sq);
            d = av0.w - bv0.w; sq = fmaf(d, d, sq);
            d = av1.x - bv1.x; sq = fmaf(d, d, sq);
            d = av1.y - bv1.y; sq = fmaf(d, d, sq);
            d = av1.z - bv1.z; sq = fmaf(d, d, sq);
            d = av1.w - bv1.w; sq = fmaf(d, d, sq);
            const float nrm = sqrtf(sq);
            corr = (nrm < 10.0f) ? (__expf(-nrm) - EXPN10) : 0.0f;
          }
          if (corr != 0.0f) atomicAdd(&feats[a * NJ + j], corr);
        }
      }
    }
  }
}

// ---------------------------------------------------------------------------
// Kernel 4: out[b][0:512] = x[b]; out[b][512:576] = 1024*exp(-10) + corrections
// ---------------------------------------------------------------------------
__global__ __launch_bounds__(256) void out_kernel(const float* __restrict__ x,
                                                  const float* __restrict__ feats,
                                                  float* __restrict__ out) {
  const int idx = blockIdx.x * 256 + threadIdx.x;
  if (idx >= NB * OUTC) return;
  const int b = idx / OUTC;
  const int c = idx - b * OUTC;
  out[idx] = (c < NIN) ? x[b * NIN + c] : (FEAT_BASE + feats[b * NJ + (c - NIN)]);
}

// ---------------------------------------------------------------------------
extern "C" void kernel_launch(void* const* d_in, const int* in_sizes, int n_in,
                              void* d_out, int out_size, void* d_ws, size_t ws_size,
                              hipStream_t stream) {
  const float* x = (const float*)d_in[0];   // [1024, 512]
  const float* T = (const float*)d_in[1];   // [512, 64, 8]
  float* out = (float*)d_out;               // [1024, 576]

  // workspace layout (3.5 MB total)
  float* Mp    = (float*)d_ws;                       // fp32 [64][1024][8]  2 MB
  float* feats = Mp + (size_t)NJ * NB * NK;          // fp32 [1024][64]   256 KB
  float* na    = feats + (size_t)NB * NJ;            // fp32 [64][1024]   256 KB
  uint4* Mb    = (uint4*)(na + (size_t)NJ * NB);     // bf16x8 [64][1024]   1 MB

  hipMemsetAsync(Mp, 0, (size_t)NJ * NB * NK * sizeof(float), stream);
  hipMemsetAsync(feats, 0, (size_t)NB * NJ * sizeof(float), stream);

  gemm_kernel<<<dim3(16, 8, 4), 256, 0, stream>>>(x, T, Mp);
  prep_kernel<<<dim3(256), 256, 0, stream>>>(Mp, Mb, na);
  pairwise_kernel<<<dim3(NJ, 8, 2), 256, 0, stream>>>(Mb, na, Mp, feats);
  out_kernel<<<dim3((NB * OUTC + 255) / 256), 256, 0, stream>>>(x, feats, out);
}

// Round 4
// 88.069 us; speedup vs baseline: 1.7988x; 1.7988x over previous
//
#include <hip/hip_runtime.h>

// Problem constants
constexpr int NB  = 1024;
constexpr int NIN = 512;
constexpr int NJ  = 64;
constexpr int NK  = 8;
constexpr int NC  = NJ * NK;          // 512
constexpr int OUTC = NIN + NJ;        // 576
constexpr float EXPN10 = 4.5399929762484854e-05f;
constexpr float FEAT_BASE = 1024.0f * EXPN10;

typedef __bf16 bf16x8 __attribute__((ext_vector_type(8)));
typedef float floatx16 __attribute__((ext_vector_type(16)));

__device__ __forceinline__ unsigned f2bf(float f) {  // RNE fp32->bf16
  unsigned u = __float_as_uint(f);
  u += 0x7FFFu + ((u >> 16) & 1u);
  return u >> 16;
}

// ---------------------------------------------------------------------------
// conv_x: x fp32 [1024][512] -> xb bf16 [1024][512] (uint4 = 8 bf16)
// ---------------------------------------------------------------------------
__global__ __launch_bounds__(256) void conv_x_kernel(const float* __restrict__ x,
                                                     uint4* __restrict__ xb) {
  const int idx = blockIdx.x * 256 + threadIdx.x;       // 0..65535
  const float4 v0 = ((const float4*)x)[idx * 2];
  const float4 v1 = ((const float4*)x)[idx * 2 + 1];
  uint4 p;
  p.x = f2bf(v0.x) | (f2bf(v0.y) << 16);
  p.y = f2bf(v0.z) | (f2bf(v0.w) << 16);
  p.z = f2bf(v1.x) | (f2bf(v1.y) << 16);
  p.w = f2bf(v1.z) | (f2bf(v1.w) << 16);
  xb[idx] = p;
}

// ---------------------------------------------------------------------------
// conv_T: T fp32 [i=512][c=512] -> Tt bf16 [c=512][i=512], LDS 64x64 transpose
// ---------------------------------------------------------------------------
__global__ __launch_bounds__(256) void conv_T_kernel(const float* __restrict__ T,
                                                     ushort* __restrict__ Tt) {
  __shared__ float Ts[64][65];
  const int tid = threadIdx.x;
  const int i0 = blockIdx.x * 64;
  const int c0 = blockIdx.y * 64;

  const int ti4 = (tid >> 4) * 4;
  const int tc  = (tid & 15) * 4;
#pragma unroll
  for (int r = 0; r < 4; ++r) {
    const float4 v = *(const float4*)&T[(i0 + ti4 + r) * NC + c0 + tc];
    Ts[tc + 0][ti4 + r] = v.x;
    Ts[tc + 1][ti4 + r] = v.y;
    Ts[tc + 2][ti4 + r] = v.z;
    Ts[tc + 3][ti4 + r] = v.w;
  }
  __syncthreads();

  const int co = tid >> 2;          // 0..63
  const int io = (tid & 3) * 16;    // 0,16,32,48
  uint4 p0, p1;
  unsigned w[8];
#pragma unroll
  for (int q = 0; q < 8; ++q)
    w[q] = f2bf(Ts[co][io + 2 * q]) | (f2bf(Ts[co][io + 2 * q + 1]) << 16);
  p0.x = w[0]; p0.y = w[1]; p0.z = w[2]; p0.w = w[3];
  p1.x = w[4]; p1.y = w[5]; p1.z = w[6]; p1.w = w[7];
  uint4* dst = (uint4*)&Tt[(size_t)(c0 + co) * NIN + i0 + io];
  dst[0] = p0;
  dst[1] = p1;
}

// ---------------------------------------------------------------------------
// gemm: Cpart[z][b][c] = sum_{i in z-chunk} xb[b][i] * Tt[c][i]
// Grid (16 b-tiles, 8 c-tiles, 4 k-chunks) = 512 blocks, 4 waves each.
// Block tile 64x64, K-chunk 128. MFMA 32x32x16 bf16, one 32x32 tile per wave.
// LDS stride 136 bf16 (pad 8) -> 4-way max bank aliasing on ds_read_b128.
// ---------------------------------------------------------------------------
__global__ __launch_bounds__(256) void gemm_kernel(const uint4* __restrict__ xb,
                                                   const uint4* __restrict__ ttb,
                                                   float* __restrict__ Cpart) {
  __shared__ __align__(16) __bf16 Xs[64 * 136];
  __shared__ __align__(16) __bf16 Ts[64 * 136];

  const int tid = threadIdx.x;
  const int b0 = blockIdx.x * 64;
  const int c0 = blockIdx.y * 64;
  const int z  = blockIdx.z;          // k-chunk: i in [z*128, z*128+128)

  // stage: 64 rows x 16 uint4 per operand, 4 uint4 per thread each
#pragma unroll
  for (int t = 0; t < 4; ++t) {
    const int u = t * 256 + tid;
    const int row = u >> 4, seg = u & 15;
    *(uint4*)&Xs[row * 136 + seg * 8] = xb[(b0 + row) * 64 + z * 16 + seg];
    *(uint4*)&Ts[row * 136 + seg * 8] = ttb[(c0 + row) * 64 + z * 16 + seg];
  }
  __syncthreads();

  const int lane = tid & 63;
  const int w    = tid >> 6;
  const int l31  = lane & 31;
  const int half = lane >> 5;
  const int arow = (w & 1) * 32 + l31;
  const int bcol = (w >> 1) * 32 + l31;

  floatx16 acc = {};
#pragma unroll
  for (int s = 0; s < 8; ++s) {
    const bf16x8 af = *(const bf16x8*)&Xs[arow * 136 + s * 16 + half * 8];
    const bf16x8 bf = *(const bf16x8*)&Ts[bcol * 136 + s * 16 + half * 8];
    acc = __builtin_amdgcn_mfma_f32_32x32x16_bf16(af, bf, acc, 0, 0, 0);
  }

  float* out = Cpart + (size_t)z * NB * NC;
#pragma unroll
  for (int reg = 0; reg < 16; ++reg) {
    const int row = (reg & 3) + 8 * (reg >> 2) + 4 * half;
    out[(b0 + (w & 1) * 32 + row) * NC + c0 + (w >> 1) * 32 + l31] = acc[reg];
  }
}

// ---------------------------------------------------------------------------
// reduce: sum 4 k-chunk partials -> Mp fp32 [j][b][8], Mb bf16x8, na = |M|^2
// idx = j*1024 + b  (coalesced writes; scattered 32B reads hit L2)
// ---------------------------------------------------------------------------
__global__ __launch_bounds__(256) void reduce_kernel(const float* __restrict__ Cpart,
                                                     float* __restrict__ Mp,
                                                     uint4* __restrict__ Mb,
                                                     float* __restrict__ na) {
  const int idx = blockIdx.x * 256 + threadIdx.x;   // 0..65535
  const int j = idx >> 10, b = idx & 1023;
  float4 m0 = {0.f, 0.f, 0.f, 0.f}, m1 = {0.f, 0.f, 0.f, 0.f};
#pragma unroll
  for (int z = 0; z < 4; ++z) {
    const float* src = Cpart + ((size_t)z * NB + b) * NC + j * 8;
    const float4 v0 = *(const float4*)src;
    const float4 v1 = *(const float4*)(src + 4);
    m0.x += v0.x; m0.y += v0.y; m0.z += v0.z; m0.w += v0.w;
    m1.x += v1.x; m1.y += v1.y; m1.z += v1.z; m1.w += v1.w;
  }
  ((float4*)Mp)[idx * 2]     = m0;
  ((float4*)Mp)[idx * 2 + 1] = m1;
  float s = m0.x * m0.x;
  s = fmaf(m0.y, m0.y, s); s = fmaf(m0.z, m0.z, s); s = fmaf(m0.w, m0.w, s);
  s = fmaf(m1.x, m1.x, s); s = fmaf(m1.y, m1.y, s); s = fmaf(m1.z, m1.z, s);
  s = fmaf(m1.w, m1.w, s);
  na[idx] = s;
  uint4 p;
  p.x = f2bf(m0.x) | (f2bf(m0.y) << 16);
  p.y = f2bf(m0.z) | (f2bf(m0.w) << 16);
  p.z = f2bf(m1.x) | (f2bf(m1.y) << 16);
  p.w = f2bf(m1.z) | (f2bf(m1.w) << 16);
  Mb[idx] = p;
}

// ---------------------------------------------------------------------------
// pairwise via MFMA + exact per-pair prefilter.
// flag iff 0.995*(na+nb) - 2P < 100  (<=> sq_est < 100 + 0.005S; bf16 error
// |2dP| <= S/256 < 0.005S -> no false negatives; FP rate ~1e-5 -> rare path
// fires ~only on diagonal tiles). Rare path: exact fp32 recompute from Mp.
// ---------------------------------------------------------------------------
__global__ __launch_bounds__(256) void pairwise_kernel(const uint4* __restrict__ Mb,
                                                       const float* __restrict__ na,
                                                       const float* __restrict__ Mp,
                                                       float* __restrict__ feats) {
  const int j    = blockIdx.x;
  const int ag   = blockIdx.y;
  const int bh   = blockIdx.z;
  const int tid  = threadIdx.x;
  const int lane = tid & 63;
  const int w    = tid >> 6;
  const int col  = lane & 31;
  const int h    = lane >> 5;
  const int jb   = j * NB;

  __shared__ uint4 Mb_s[513];    // [512] = zeros for K-pad lanes
  __shared__ float nb_s[512];
  __shared__ float na_s[128];

  const int bbeg = bh * 512;
  Mb_s[tid]       = Mb[jb + bbeg + tid];
  Mb_s[tid + 256] = Mb[jb + bbeg + tid + 256];
  nb_s[tid]       = na[jb + bbeg + tid];
  nb_s[tid + 256] = na[jb + bbeg + tid + 256];
  if (tid == 0) Mb_s[512] = uint4{0u, 0u, 0u, 0u};

  const int a0 = ag * 128 + w * 32;
  if (lane < 32) na_s[w * 32 + lane] = na[jb + a0 + lane];

  uint4 araw = uint4{0u, 0u, 0u, 0u};
  if (lane < 32) araw = Mb[jb + a0 + lane];
  const bf16x8 af = __builtin_bit_cast(bf16x8, araw);

  __syncthreads();

  // per-lane 0.995*na for the 16 rows this lane's regs cover
  float c995[16];
#pragma unroll
  for (int reg = 0; reg < 16; ++reg) {
    const int row = (reg & 3) + 8 * (reg >> 2) + 4 * h;
    c995[reg] = 0.995f * na_s[w * 32 + row];
  }

  const floatx16 zero = {};

#pragma unroll 2
  for (int bt = 0; bt < 16; ++bt) {
    const int bidx = bt * 32 + col;
    const uint4 braw = Mb_s[lane < 32 ? bidx : 512];
    const bf16x8 bf = __builtin_bit_cast(bf16x8, braw);
    const floatx16 P = __builtin_amdgcn_mfma_f32_32x32x16_bf16(af, bf, zero, 0, 0, 0);
    const float nb_l = nb_s[bidx];
    const float rhs = 100.0f - 0.995f * nb_l;

    float t = fmaf(-2.0f, P[0], c995[0]);
#pragma unroll
    for (int reg = 1; reg < 16; ++reg)
      t = fminf(t, fmaf(-2.0f, P[reg], c995[reg]));

    if (__any(t < rhs)) {   // rare: ~diagonal tiles only
#pragma unroll
      for (int reg = 0; reg < 16; ++reg) {
        if (fmaf(-2.0f, P[reg], c995[reg]) < rhs) {
          const int row = (reg & 3) + 8 * (reg >> 2) + 4 * h;
          const int a = a0 + row;
          const int b = bbeg + bt * 32 + col;
          float corr;
          if (a == b) {
            corr = 1.0f - EXPN10;
          } else {
            const float4 av0 = ((const float4*)Mp)[(jb + a) * 2];
            const float4 av1 = ((const float4*)Mp)[(jb + a) * 2 + 1];
            const float4 bv0 = ((const float4*)Mp)[(jb + b) * 2];
            const float4 bv1 = ((const float4*)Mp)[(jb + b) * 2 + 1];
            float d = av0.x - bv0.x; float sq = d * d;
            d = av0.y - bv0.y; sq = fmaf(d, d, sq);
            d = av0.z - bv0.z; sq = fmaf(d, d, sq);
            d = av0.w - bv0.w; sq = fmaf(d, d, sq);
            d = av1.x - bv1.x; sq = fmaf(d, d, sq);
            d = av1.y - bv1.y; sq = fmaf(d, d, sq);
            d = av1.z - bv1.z; sq = fmaf(d, d, sq);
            d = av1.w - bv1.w; sq = fmaf(d, d, sq);
            const float nrm = sqrtf(sq);
            corr = (nrm < 10.0f) ? (__expf(-nrm) - EXPN10) : 0.0f;
          }
          if (corr != 0.0f) atomicAdd(&feats[a * NJ + j], corr);
        }
      }
    }
  }
}

// ---------------------------------------------------------------------------
__global__ __launch_bounds__(256) void out_kernel(const float* __restrict__ x,
                                                  const float* __restrict__ feats,
                                                  float* __restrict__ out) {
  const int idx = blockIdx.x * 256 + threadIdx.x;
  if (idx >= NB * OUTC) return;
  const int b = idx / OUTC;
  const int c = idx - b * OUTC;
  out[idx] = (c < NIN) ? x[b * NIN + c] : (FEAT_BASE + feats[b * NJ + (c - NIN)]);
}

// ---------------------------------------------------------------------------
extern "C" void kernel_launch(void* const* d_in, const int* in_sizes, int n_in,
                              void* d_out, int out_size, void* d_ws, size_t ws_size,
                              hipStream_t stream) {
  const float* x = (const float*)d_in[0];
  const float* T = (const float*)d_in[1];
  float* out = (float*)d_out;

  // workspace layout (13.75 MB)
  float* Cpart = (float*)d_ws;                        // [4][1024][512] fp32  8 MB
  float* Mp    = Cpart + (size_t)4 * NB * NC;         // [64][1024][8] fp32   2 MB
  float* feats = Mp + (size_t)NJ * NB * NK;           // [1024][64]         256 KB
  float* na    = feats + (size_t)NB * NJ;             // [64][1024]         256 KB
  uint4* Mb    = (uint4*)(na + (size_t)NJ * NB);      // [64][1024] bf16x8    1 MB
  uint4* xb    = Mb + (size_t)NJ * NB;                // [1024][512] bf16     1 MB
  ushort* Tt   = (ushort*)(xb + (size_t)NB * NIN / 8);// [512][512] bf16    0.5 MB

  hipMemsetAsync(feats, 0, (size_t)NB * NJ * sizeof(float), stream);

  conv_x_kernel<<<dim3(256), 256, 0, stream>>>(x, xb);
  conv_T_kernel<<<dim3(8, 8), 256, 0, stream>>>(T, Tt);
  gemm_kernel<<<dim3(16, 8, 4), 256, 0, stream>>>(xb, (const uint4*)Tt, Cpart);
  reduce_kernel<<<dim3(256), 256, 0, stream>>>(Cpart, Mp, Mb, na);
  pairwise_kernel<<<dim3(NJ, 8, 2), 256, 0, stream>>>(Mb, na, Mp, feats);
  out_kernel<<<dim3((NB * OUTC + 255) / 256), 256, 0, stream>>>(x, feats, out);
}

// Round 5
// 76.583 us; speedup vs baseline: 2.0686x; 1.1500x over previous
//
#include <hip/hip_runtime.h>

// Problem constants
constexpr int NB  = 1024;
constexpr int NIN = 512;
constexpr int NJ  = 64;
constexpr int NK  = 8;
constexpr int NC  = NJ * NK;          // 512
constexpr int OUTC = NIN + NJ;        // 576
constexpr float EXPN10 = 4.5399929762484854e-05f;
constexpr float FEAT_BASE = 1024.0f * EXPN10;

typedef __bf16 bf16x8 __attribute__((ext_vector_type(8)));
typedef float floatx16 __attribute__((ext_vector_type(16)));

__device__ __forceinline__ unsigned f2bf(float f) {  // RNE fp32->bf16
  unsigned u = __float_as_uint(f);
  u += 0x7FFFu + ((u >> 16) & 1u);
  return u >> 16;
}

// ---------------------------------------------------------------------------
// Kernel 1 (fused): role-switched on blockIdx.x
//   [0,256)    : x fp32 -> xb bf16
//   [256,320)  : T fp32 [i][c] -> Tt bf16 [c][i] (64x64 LDS transpose tiles)
//   [320,2624) : out init — out[b][0:512]=x[b], out[b][512:576]=FEAT_BASE
// ---------------------------------------------------------------------------
__global__ __launch_bounds__(256) void conv_init_kernel(const float* __restrict__ x,
                                                        const float* __restrict__ T,
                                                        uint4* __restrict__ xb,
                                                        ushort* __restrict__ Tt,
                                                        float* __restrict__ out) {
  __shared__ float Ts[64][65];
  const int bid = blockIdx.x;
  const int tid = threadIdx.x;

  if (bid < 256) {              // ---- conv_x ----
    const int idx = bid * 256 + tid;            // 0..65535
    const float4 v0 = ((const float4*)x)[idx * 2];
    const float4 v1 = ((const float4*)x)[idx * 2 + 1];
    uint4 p;
    p.x = f2bf(v0.x) | (f2bf(v0.y) << 16);
    p.y = f2bf(v0.z) | (f2bf(v0.w) << 16);
    p.z = f2bf(v1.x) | (f2bf(v1.y) << 16);
    p.w = f2bf(v1.z) | (f2bf(v1.w) << 16);
    xb[idx] = p;
  } else if (bid < 320) {       // ---- conv_T (transpose + bf16) ----
    const int t = bid - 256;
    const int i0 = (t & 7) * 64;
    const int c0 = (t >> 3) * 64;

    const int ti4 = (tid >> 4) * 4;
    const int tc  = (tid & 15) * 4;
#pragma unroll
    for (int r = 0; r < 4; ++r) {
      const float4 v = *(const float4*)&T[(i0 + ti4 + r) * NC + c0 + tc];
      Ts[tc + 0][ti4 + r] = v.x;
      Ts[tc + 1][ti4 + r] = v.y;
      Ts[tc + 2][ti4 + r] = v.z;
      Ts[tc + 3][ti4 + r] = v.w;
    }
    __syncthreads();

    const int co = tid >> 2;
    const int io = (tid & 3) * 16;
    unsigned w[8];
#pragma unroll
    for (int q = 0; q < 8; ++q)
      w[q] = f2bf(Ts[co][io + 2 * q]) | (f2bf(Ts[co][io + 2 * q + 1]) << 16);
    uint4* dst = (uint4*)&Tt[(size_t)(c0 + co) * NIN + i0 + io];
    dst[0] = uint4{w[0], w[1], w[2], w[3]};
    dst[1] = uint4{w[4], w[5], w[6], w[7]};
  } else {                      // ---- out init ----
    const int idx = (bid - 320) * 256 + tid;    // 0..589823
    const int b = idx / OUTC;
    const int c = idx - b * OUTC;
    out[idx] = (c < NIN) ? x[b * NIN + c] : FEAT_BASE;
  }
}

// ---------------------------------------------------------------------------
// Kernel 2: gemm, full K=512, 128 blocks (16 b-tiles x 8 c-tiles), 4 waves.
// Block tile 64x64, BK=128 (4 chunks). MFMA 32x32x16 bf16.
// Writes Mp[j][b][k] directly (32B-granule scatter, L2-absorbed).
// ---------------------------------------------------------------------------
__global__ __launch_bounds__(256) void gemm_kernel(const uint4* __restrict__ xb,
                                                   const uint4* __restrict__ ttb,
                                                   float* __restrict__ Mp) {
  __shared__ __align__(16) __bf16 Xs[64 * 136];
  __shared__ __align__(16) __bf16 Ts[64 * 136];

  const int tid = threadIdx.x;
  const int b0 = blockIdx.x * 64;
  const int c0 = blockIdx.y * 64;

  const int lane = tid & 63;
  const int w    = tid >> 6;
  const int l31  = lane & 31;
  const int half = lane >> 5;
  const int arow = (w & 1) * 32 + l31;
  const int bcol = (w >> 1) * 32 + l31;

  floatx16 acc = {};

  for (int z = 0; z < 4; ++z) {
#pragma unroll
    for (int t = 0; t < 4; ++t) {
      const int u = t * 256 + tid;
      const int row = u >> 4, seg = u & 15;
      *(uint4*)&Xs[row * 136 + seg * 8] = xb[(b0 + row) * 64 + z * 16 + seg];
      *(uint4*)&Ts[row * 136 + seg * 8] = ttb[(c0 + row) * 64 + z * 16 + seg];
    }
    __syncthreads();

#pragma unroll
    for (int s = 0; s < 8; ++s) {
      const bf16x8 af = *(const bf16x8*)&Xs[arow * 136 + s * 16 + half * 8];
      const bf16x8 bf = *(const bf16x8*)&Ts[bcol * 136 + s * 16 + half * 8];
      acc = __builtin_amdgcn_mfma_f32_32x32x16_bf16(af, bf, acc, 0, 0, 0);
    }
    __syncthreads();
  }

#pragma unroll
  for (int reg = 0; reg < 16; ++reg) {
    const int row = (reg & 3) + 8 * (reg >> 2) + 4 * half;
    const int b = b0 + (w & 1) * 32 + row;
    const int c = c0 + (w >> 1) * 32 + l31;
    Mp[((c >> 3) * NB + b) * NK + (c & 7)] = acc[reg];
  }
}

// ---------------------------------------------------------------------------
// Kernel 3: prep — Mb bf16x8 + na = |M|^2 from Mp (all coalesced, 3.25 MB)
// ---------------------------------------------------------------------------
__global__ __launch_bounds__(256) void prep_kernel(const float* __restrict__ Mp,
                                                   uint4* __restrict__ Mb,
                                                   float* __restrict__ na) {
  const int idx = blockIdx.x * 256 + threadIdx.x;   // j*1024+b
  const float4 m0 = ((const float4*)Mp)[idx * 2];
  const float4 m1 = ((const float4*)Mp)[idx * 2 + 1];
  float s = m0.x * m0.x;
  s = fmaf(m0.y, m0.y, s); s = fmaf(m0.z, m0.z, s); s = fmaf(m0.w, m0.w, s);
  s = fmaf(m1.x, m1.x, s); s = fmaf(m1.y, m1.y, s); s = fmaf(m1.z, m1.z, s);
  s = fmaf(m1.w, m1.w, s);
  na[idx] = s;
  uint4 p;
  p.x = f2bf(m0.x) | (f2bf(m0.y) << 16);
  p.y = f2bf(m0.z) | (f2bf(m0.w) << 16);
  p.z = f2bf(m1.x) | (f2bf(m1.y) << 16);
  p.w = f2bf(m1.z) | (f2bf(m1.w) << 16);
  Mb[idx] = p;
}

// ---------------------------------------------------------------------------
// Kernel 4: pairwise via MFMA + exact per-pair prefilter; corrections go
// straight into out[b][512+j] (out pre-initialized with FEAT_BASE).
// flag iff 0.995*(na+nb) - 2P < 100 (no false negatives; FP rate ~1e-5).
// ---------------------------------------------------------------------------
__global__ __launch_bounds__(256) void pairwise_kernel(const uint4* __restrict__ Mb,
                                                       const float* __restrict__ na,
                                                       const float* __restrict__ Mp,
                                                       float* __restrict__ out) {
  const int j    = blockIdx.x;
  const int ag   = blockIdx.y;
  const int bh   = blockIdx.z;
  const int tid  = threadIdx.x;
  const int lane = tid & 63;
  const int w    = tid >> 6;
  const int col  = lane & 31;
  const int h    = lane >> 5;
  const int jb   = j * NB;

  __shared__ uint4 Mb_s[513];    // [512] = zeros for K-pad lanes
  __shared__ float nb_s[512];
  __shared__ float na_s[128];

  const int bbeg = bh * 512;
  Mb_s[tid]       = Mb[jb + bbeg + tid];
  Mb_s[tid + 256] = Mb[jb + bbeg + tid + 256];
  nb_s[tid]       = na[jb + bbeg + tid];
  nb_s[tid + 256] = na[jb + bbeg + tid + 256];
  if (tid == 0) Mb_s[512] = uint4{0u, 0u, 0u, 0u};

  const int a0 = ag * 128 + w * 32;
  if (lane < 32) na_s[w * 32 + lane] = na[jb + a0 + lane];

  uint4 araw = uint4{0u, 0u, 0u, 0u};
  if (lane < 32) araw = Mb[jb + a0 + lane];
  const bf16x8 af = __builtin_bit_cast(bf16x8, araw);

  __syncthreads();

  float c995[16];
#pragma unroll
  for (int reg = 0; reg < 16; ++reg) {
    const int row = (reg & 3) + 8 * (reg >> 2) + 4 * h;
    c995[reg] = 0.995f * na_s[w * 32 + row];
  }

  const floatx16 zero = {};

#pragma unroll 2
  for (int bt = 0; bt < 16; ++bt) {
    const int bidx = bt * 32 + col;
    const uint4 braw = Mb_s[lane < 32 ? bidx : 512];
    const bf16x8 bf = __builtin_bit_cast(bf16x8, braw);
    const floatx16 P = __builtin_amdgcn_mfma_f32_32x32x16_bf16(af, bf, zero, 0, 0, 0);
    const float nb_l = nb_s[bidx];
    const float rhs = 100.0f - 0.995f * nb_l;

    float t = fmaf(-2.0f, P[0], c995[0]);
#pragma unroll
    for (int reg = 1; reg < 16; ++reg)
      t = fminf(t, fmaf(-2.0f, P[reg], c995[reg]));

    if (__any(t < rhs)) {   // rare: ~diagonal tiles only
#pragma unroll
      for (int reg = 0; reg < 16; ++reg) {
        if (fmaf(-2.0f, P[reg], c995[reg]) < rhs) {
          const int row = (reg & 3) + 8 * (reg >> 2) + 4 * h;
          const int a = a0 + row;
          const int b = bbeg + bt * 32 + col;
          float corr;
          if (a == b) {
            corr = 1.0f - EXPN10;
          } else {
            const float4 av0 = ((const float4*)Mp)[(jb + a) * 2];
            const float4 av1 = ((const float4*)Mp)[(jb + a) * 2 + 1];
            const float4 bv0 = ((const float4*)Mp)[(jb + b) * 2];
            const float4 bv1 = ((const float4*)Mp)[(jb + b) * 2 + 1];
            float d = av0.x - bv0.x; float sq = d * d;
            d = av0.y - bv0.y; sq = fmaf(d, d, sq);
            d = av0.z - bv0.z; sq = fmaf(d, d, sq);
            d = av0.w - bv0.w; sq = fmaf(d, d, sq);
            d = av1.x - bv1.x; sq = fmaf(d, d, sq);
            d = av1.y - bv1.y; sq = fmaf(d, d, sq);
            d = av1.z - bv1.z; sq = fmaf(d, d, sq);
            d = av1.w - bv1.w; sq = fmaf(d, d, sq);
            const float nrm = sqrtf(sq);
            corr = (nrm < 10.0f) ? (__expf(-nrm) - EXPN10) : 0.0f;
          }
          if (corr != 0.0f) atomicAdd(&out[a * OUTC + NIN + j], corr);
        }
      }
    }
  }
}

// ---------------------------------------------------------------------------
extern "C" void kernel_launch(void* const* d_in, const int* in_sizes, int n_in,
                              void* d_out, int out_size, void* d_ws, size_t ws_size,
                              hipStream_t stream) {
  const float* x = (const float*)d_in[0];
  const float* T = (const float*)d_in[1];
  float* out = (float*)d_out;

  // workspace layout (4.75 MB)
  float* Mp  = (float*)d_ws;                         // [64][1024][8] fp32   2 MB
  float* na  = Mp + (size_t)NJ * NB * NK;            // [64][1024]         256 KB
  uint4* Mb  = (uint4*)(na + (size_t)NJ * NB);       // [64][1024] bf16x8    1 MB
  uint4* xb  = Mb + (size_t)NJ * NB;                 // [1024][512] bf16     1 MB
  ushort* Tt = (ushort*)(xb + (size_t)NB * NIN / 8); // [512][512] bf16    0.5 MB

  conv_init_kernel<<<dim3(2624), 256, 0, stream>>>(x, T, xb, Tt, out);
  gemm_kernel<<<dim3(16, 8), 256, 0, stream>>>(xb, (const uint4*)Tt, Mp);
  prep_kernel<<<dim3(256), 256, 0, stream>>>(Mp, Mb, na);
  pairwise_kernel<<<dim3(NJ, 8, 2), 256, 0, stream>>>(Mb, na, Mp, out);
}